// Round 7
// baseline (210.220 us; speedup 1.0000x reference)
//
#include <hip/hip_runtime.h>

// Problem constants
#define N_ROWS 16384   // B*T
#define C_DIM  1024
#define GV     640     // G*V
#define V_DIM  320
#define G_DIM  2
#define D_DIM  256
#define MROWS  64      // rows per fused block
#define FBLKS  (N_ROWS / MROWS)  // 256 = exactly 1 block/CU
#define NBUCKET 64

typedef __attribute__((ext_vector_type(8))) _Float16 half8;
typedef __attribute__((ext_vector_type(4))) _Float16 half4v;
typedef __attribute__((ext_vector_type(4))) float float4v;

#define LDS_AS(p) ((__attribute__((address_space(3))) unsigned int*)(p))
#define GLB_AS(p) ((const __attribute__((address_space(1))) unsigned int*)(p))

// ---------------- W -> fp16 hi, pre-swizzled into 16B-chunk-transposed layout ----
// whT[((kb*4 + c)*640 + n)*8 + h] = (half)W[n][kb*32 + c*8 + h]
// Also zeroes the mf/mi atomic-partial region (81,920 threads x 4 B = 327,680 B).
__global__ __launch_bounds__(256) void wsplit_kernel(const float* __restrict__ src,
                                                     _Float16* __restrict__ dst,
                                                     int* __restrict__ zr) {
  const int t = blockIdx.x * 256 + threadIdx.x;  // 0..81919
  zr[t] = 0;
  const int n = t % GV;
  const int cc = t / GV;       // 0..127 ; k = cc*8
  const int k = cc * 8;
  const float4 v0 = *(const float4*)(src + (size_t)n * C_DIM + k);
  const float4 v1 = *(const float4*)(src + (size_t)n * C_DIM + k + 4);
  half8 h;
  h[0] = (_Float16)v0.x; h[1] = (_Float16)v0.y; h[2] = (_Float16)v0.z; h[3] = (_Float16)v0.w;
  h[4] = (_Float16)v1.x; h[5] = (_Float16)v1.y; h[6] = (_Float16)v1.z; h[7] = (_Float16)v1.w;
  *(half8*)(dst + (size_t)t * 8) = h;
}

// ---------------- Fused: GEMM (M=64 x N=640 per block) + in-acc epilogue ----------
// GEMM loop: software-pipelined with COUNTED vmcnt (T4). The old __syncthreads()
// per iter compiled to "s_waitcnt vmcnt(0) lgkmcnt(0); s_barrier" -> full drain of
// the just-issued next-tile staging every iteration (the 2-phase structural stall;
// at 1 block/CU there is no TLP to hide it). New structure per iter:
//   stage(kb+1) issue | splitA (implicit vmcnt<=5 retires PREV iter's 5 B-loads,
//   leaves the new 5 in flight) | a4 prefetch | s_waitcnt vmcnt(6) lgkmcnt(0) |
//   s_barrier | ds_read+MFMA | s_barrier
// Next-tile loads thus have a full MFMA phase to land. Last iter peeled (vmcnt(0)).
// Epilogue identical to round 6 (in-acc, no Ldump).
__global__ __launch_bounds__(512, 2) void fused_kernel(
    const float* __restrict__ x,       // [N_ROWS, C_DIM] fp32
    const _Float16* __restrict__ whT,  // swizzled fp16 hi of W
    const float* __restrict__ bias,    // [GV]
    const float* __restrict__ gn,      // [2*N_ROWS, V_DIM]
    const float* __restrict__ cb,      // [GV, D_DIM]
    float* __restrict__ q,             // [N_ROWS, 512]
    float* __restrict__ mf,            // [NBUCKET, GV] atomic softmax partials (pre-zeroed)
    int* __restrict__ mi) {            // [NBUCKET, GV] atomic argmax counts (pre-zeroed)
  // LDS map: GEMM: B 2x40960 | A-hi 2x4096 | A-lo 2x4096 = 98304 B
  //   epilogue reuse: combW[128 rows][36 dwords] = 18,432 B ; wbL[128][4] at +18432
  __shared__ __align__(16) char smemU[98304];
  _Float16* BhL = (_Float16*)smemU;
  _Float16* AhL = (_Float16*)(smemU + 81920);
  _Float16* AlL = (_Float16*)(smemU + 90112);
  float* combW  = (float*)smemU;
  float* wbL    = (float*)(smemU + 18432);
  __shared__ float accL[GV];
  __shared__ int   cntL[GV];

  const int tid = threadIdx.x;
  const int lane = tid & 63;
  const int w = tid >> 6;          // wave 0..7
  const int m0 = blockIdx.x * MROWS;
  const int frow = lane & 15;
  const int quad = lane >> 4;

  for (int e = tid; e < GV; e += 512) { accL[e] = 0.0f; cntL[e] = 0; }

  // A staging map: thread -> (row ar, 4-float k-chunk ak) of 64x32 fp32 tile
  const int ar = tid >> 3;           // 0..63
  const int ak = (tid & 7) * 4;      // 0,4,...,28
  const int ac = ak >> 3;            // chunk 0..3
  const int ah_off = ak & 7;         // 0 or 4 within 8-half chunk
  const float* xp = x + (size_t)(m0 + ar) * C_DIM + ak;

  float4v acc[4][5];
#pragma unroll
  for (int i = 0; i < 4; ++i)
#pragma unroll
    for (int j = 0; j < 5; ++j) acc[i][j] = (float4v)0.0f;

  auto stageB = [&](int kb, _Float16* Bh) {
    const _Float16* bsrc = whT + (size_t)kb * 2560 * 8;
#pragma unroll
    for (int s = 0; s < 5; ++s) {
      const int c = s * 512 + tid;   // 2560 16B chunks, lane-linear both sides
      __builtin_amdgcn_global_load_lds(GLB_AS(bsrc + (size_t)c * 8),
                                       LDS_AS(Bh + c * 8), 16, 0, 0);
    }
  };
  auto splitA = [&](const float4& a4, _Float16* Ah, _Float16* Al) {
    const _Float16 h0 = (_Float16)a4.x, h1 = (_Float16)a4.y;
    const _Float16 h2 = (_Float16)a4.z, h3 = (_Float16)a4.w;
    half4v hv, lv;
    hv[0] = h0; hv[1] = h1; hv[2] = h2; hv[3] = h3;
    lv[0] = (_Float16)(a4.x - (float)h0);
    lv[1] = (_Float16)(a4.y - (float)h1);
    lv[2] = (_Float16)(a4.z - (float)h2);
    lv[3] = (_Float16)(a4.w - (float)h3);
    *(half4v*)&Ah[(ac * 64 + ar) * 8 + ah_off] = hv;
    *(half4v*)&Al[(ac * 64 + ar) * 8 + ah_off] = lv;
  };
  auto mfmaPhase = [&](_Float16* BhC, _Float16* AhC, _Float16* AlC) {
    half8 ah[4], al[4];
#pragma unroll
    for (int i = 0; i < 4; ++i) {
      ah[i] = *(const half8*)&AhC[(quad * 64 + 16 * i + frow) * 8];
      al[i] = *(const half8*)&AlC[(quad * 64 + 16 * i + frow) * 8];
    }
#pragma unroll
    for (int j = 0; j < 5; ++j) {
      const half8 bh = *(const half8*)&BhC[(quad * 640 + 80 * w + 16 * j + frow) * 8];
#pragma unroll
      for (int i = 0; i < 4; ++i) {
        acc[i][j] = __builtin_amdgcn_mfma_f32_16x16x32_f16(ah[i], bh, acc[i][j], 0, 0, 0);
        acc[i][j] = __builtin_amdgcn_mfma_f32_16x16x32_f16(al[i], bh, acc[i][j], 0, 0, 0);
      }
    }
  };

  // ---- prologue: a4(kb=0) -> stage(0) -> splitA -> a4(kb=1); no barrier needed
  // (the first loop iteration's counted wait + barrier covers it)
  float4 a4 = *(const float4*)xp;
  stageB(0, BhL);
  splitA(a4, AhL, AlL);
  a4 = *(const float4*)(xp + 32);

  // ---- main loop: iters 0..30 pipelined; iter 31 peeled ----
  for (int kb = 0; kb < 31; ++kb) {
    const int cur = kb & 1;
    const int nxt = cur ^ 1;

    stageB(kb + 1, BhL + nxt * 20480);                 // 5 loads, stay in flight
    splitA(a4, AhL + nxt * 2048, AlL + nxt * 2048);    // implicit vmcnt<=5: retires S5(kb)
    if (kb < 30) a4 = *(const float4*)(xp + (kb + 2) * 32);

    // own prev-stage retired (<=6 out: 5 new stage + 1 a4); own A ds_writes drained
    asm volatile("s_waitcnt vmcnt(6) lgkmcnt(0)" ::: "memory");
    __builtin_amdgcn_sched_barrier(0);
    __builtin_amdgcn_s_barrier();      // all waves: buf[cur] staged + A[cur] visible
    __builtin_amdgcn_sched_barrier(0);

    mfmaPhase(BhL + cur * 20480, AhL + cur * 2048, AlL + cur * 2048);

    __builtin_amdgcn_sched_barrier(0);
    __builtin_amdgcn_s_barrier();      // reads of buf[cur] done block-wide before overwrite
  }
  // peeled iter 31 (cur=1): final stage must drain fully
  asm volatile("s_waitcnt vmcnt(0) lgkmcnt(0)" ::: "memory");
  __builtin_amdgcn_sched_barrier(0);
  __builtin_amdgcn_s_barrier();
  __builtin_amdgcn_sched_barrier(0);
  mfmaPhase(BhL + 20480, AhL + 2048, AlL + 2048);

  __syncthreads();   // full drain once before LDS reuse by the epilogue

  // bias for this wave's cols
  float bw[5];
#pragma unroll
  for (int j = 0; j < 5; ++j) bw[j] = bias[80 * w + 16 * j + frow];

  const int g  = w >> 2;   // group handled by this wave
  const int wq = w & 3;    // col-slice within group: cols 80*wq + 16j + frow

  // -------- Phase A: per-row wave-slice reductions (16 rows, fully unrolled) -----
  float mlk[4][4];   // per-row wave-slice l-max (basis of stored e')
#pragma unroll
  for (int i = 0; i < 4; ++i) {
#pragma unroll
    for (int r = 0; r < 4; ++r) {
      const int row = 16 * i + 4 * quad + r;
      const int n = m0 + row;
      const float* gp = gn + (size_t)(2 * n + g) * V_DIM + 80 * wq + frow;

      float l5[5], t5[5];
#pragma unroll
      for (int j = 0; j < 5; ++j) {
        l5[j] = acc[i][j][r] + bw[j];
        t5[j] = (l5[j] + gp[16 * j]) * 0.5f;
      }
      // in-lane max + argmax (ascending j: strict > keeps first index)
      float ml = l5[0]; int il = 80 * wq + frow;
      float mt = t5[0]; int it = il;
#pragma unroll
      for (int j = 1; j < 5; ++j) {
        const int cj = 80 * wq + 16 * j + frow;
        if (l5[j] > ml) { ml = l5[j]; il = cj; }
        if (t5[j] > mt) { mt = t5[j]; it = cj; }
      }
      // 16-lane butterfly (stays within quad-group for off<16)
#pragma unroll
      for (int off = 1; off < 16; off <<= 1) {
        const float o1 = __shfl_xor(ml, off, 64); const int i1 = __shfl_xor(il, off, 64);
        if (o1 > ml || (o1 == ml && i1 < il)) { ml = o1; il = i1; }
        const float o2 = __shfl_xor(mt, off, 64); const int i2 = __shfl_xor(it, off, 64);
        if (o2 > mt || (o2 == mt && i2 < it)) { mt = o2; it = i2; }
      }
      mlk[i][r] = ml;
      // online partial sums vs wave-slice max; keep e' in acc regs
      float sl = 0.0f, st = 0.0f;
#pragma unroll
      for (int j = 0; j < 5; ++j) {
        const float el = expf(l5[j] - ml);
        acc[i][j][r] = el;
        sl += el;
        st += expf(t5[j] - mt);
      }
#pragma unroll
      for (int off = 1; off < 16; off <<= 1) {
        sl += __shfl_xor(sl, off, 64);
        st += __shfl_xor(st, off, 64);
      }
      // one writer lane per (i,r): 2 x b128 partials
      if (frow == 4 * i + r) {
        float* dst = combW + (size_t)(g * 64 + row) * 36 + wq * 8;
        float4v p1, p2;
        p1[0] = ml; p1[1] = __int_as_float(il); p1[2] = sl; p1[3] = 0.0f;
        p2[0] = mt; p2[1] = __int_as_float(it); p2[2] = st; p2[3] = 0.0f;
        *(float4v*)dst = p1;
        *(float4v*)(dst + 4) = p2;
      }
    }
  }
  __syncthreads();

  // -------- Phase A2: combine 4 wave partials per row (128 rows, 128 threads) ----
  if (tid < 128) {
    const int rg = tid;                // g*64 + row
    const float* cw = combW + (size_t)rg * 36;
    float mw[4], sw[4], tw[4], s2[4];
    int   iw[4], ti4[4];
#pragma unroll
    for (int v = 0; v < 4; ++v) {
      const float4v p1 = *(const float4v*)(cw + v * 8);
      const float4v p2 = *(const float4v*)(cw + v * 8 + 4);
      mw[v] = p1[0]; iw[v] = __float_as_int(p1[1]); sw[v] = p1[2];
      tw[v] = p2[0]; ti4[v] = __float_as_int(p2[1]); s2[v] = p2[2];
    }
    float m = mw[0]; int idx = iw[0];
    float tm = tw[0]; int ti = ti4[0];
#pragma unroll
    for (int v = 1; v < 4; ++v) {
      if (mw[v] > m || (mw[v] == m && iw[v] < idx)) { m = mw[v]; idx = iw[v]; }
      if (tw[v] > tm || (tw[v] == tm && ti4[v] < ti)) { tm = tw[v]; ti = ti4[v]; }
    }
    float sl = 0.0f, st = 0.0f;
#pragma unroll
    for (int v = 0; v < 4; ++v) {
      sl += sw[v] * expf(mw[v] - m);
      st += s2[v] * expf(tw[v] - tm);
    }
    const float inv = 1.0f / sl;
    const float sv = 1.0f / st;
    const float yv = (1.0f + sv) - sv;   // straight-through value at argmax
    const int g2 = rg >> 6;
    atomicAdd(&cntL[g2 * V_DIM + idx], 1);
    float4v wbv;
    wbv[0] = m; wbv[1] = inv; wbv[2] = yv; wbv[3] = __int_as_float(ti);
    *(float4v*)(wbL + (size_t)rg * 4) = wbv;
  }
  __syncthreads();

  // -------- Phase CD: accL accumulation + q writes --------
  float p5[5] = {0.0f, 0.0f, 0.0f, 0.0f, 0.0f};
#pragma unroll
  for (int i = 0; i < 4; ++i)
#pragma unroll
    for (int r = 0; r < 4; ++r) {
      const int row = 16 * i + 4 * quad + r;
      const float4v wbv = *(const float4v*)(wbL + (size_t)(g * 64 + row) * 4);
      const float k = expf(mlk[i][r] - wbv[0]) * wbv[1];
#pragma unroll
      for (int j = 0; j < 5; ++j) p5[j] += acc[i][j][r] * k;
    }
#pragma unroll
  for (int j = 0; j < 5; ++j)
    atomicAdd(&accL[g * V_DIM + 80 * wq + 16 * j + frow], p5[j]);  // 4-way contention

  // q: 128 tasks x 64 float4; one wave per task per iteration, fully coalesced
#pragma unroll
  for (int it2 = 0; it2 < 16; ++it2) {
    const int task = w + 8 * it2;          // 0..127 = g*64 + row
    const int tg = task >> 6, trow = task & 63;
    const float4v wbv = *(const float4v*)(wbL + (size_t)task * 4);  // broadcast
    const float yv = wbv[2];
    const int ti = __float_as_int(wbv[3]);
    const float4v c4 = ((const float4v*)cb)[(size_t)(tg * V_DIM + ti) * 64 + lane];
    float4v o4;
#pragma unroll
    for (int e2 = 0; e2 < 4; ++e2) o4[e2] = yv * c4[e2];
    ((float4v*)q)[(size_t)(m0 + trow) * 128 + tg * 64 + lane] = o4;
  }

  __syncthreads();
  const size_t pb = (size_t)(blockIdx.x & (NBUCKET - 1)) * GV;
  for (int e = tid; e < GV; e += 512) {
    atomicAdd(&mf[pb + e], accL[e]);
    atomicAdd(&mi[pb + e], cntL[e]);
  }
}

// ---------------- Finalize: sum 64 buckets, entropies, outputs ----------------
__global__ __launch_bounds__(640) void finalize_kernel(
    const float* __restrict__ mf, const int* __restrict__ mi,
    float* __restrict__ out3) {
  __shared__ float sA[G_DIM];
  __shared__ float sC[G_DIM];
  const int t = threadIdx.x;        // 0..639 == e
  if (t < G_DIM) { sA[t] = 0.0f; sC[t] = 0.0f; }
  __syncthreads();

  const int g = t / V_DIM;          // wave-uniform
  float f = 0.0f;
  int   c = 0;
#pragma unroll 8
  for (int b = 0; b < NBUCKET; ++b) {
    f += mf[(size_t)b * GV + t];
    c += mi[(size_t)b * GV + t];
  }
  const float pa = f * (1.0f / 16384.0f);
  const float ph = (float)c * (1.0f / 16384.0f);
  float a = pa * logf(pa + 1e-7f);
  float h = ph * logf(ph + 1e-7f);
#pragma unroll
  for (int off = 32; off > 0; off >>= 1) {
    a += __shfl_xor(a, off, 64);
    h += __shfl_xor(h, off, 64);
  }
  if ((t & 63) == 0) {
    atomicAdd(&sA[g], a);
    atomicAdd(&sC[g], h);
  }
  __syncthreads();
  if (t == 0) {
    const float code_p = expf(-sC[0]) + expf(-sC[1]);
    const float prob_p = expf(-sA[0]) + expf(-sA[1]);
    out3[0] = code_p;
    out3[1] = prob_p;
    out3[2] = ((float)GV - prob_p) / (float)GV;
  }
}

extern "C" void kernel_launch(void* const* d_in, const int* in_sizes, int n_in,
                              void* d_out, int out_size, void* d_ws, size_t ws_size,
                              hipStream_t stream) {
  const float* x  = (const float*)d_in[0];  // [8,2048,1024]
  const float* W  = (const float*)d_in[1];  // [640,1024]
  const float* b  = (const float*)d_in[2];  // [640]
  const float* cb = (const float*)d_in[3];  // [1,640,256]
  const float* gn = (const float*)d_in[4];  // [32768,320]
  float* out = (float*)d_out;               // q [16384*512] + 3 scalars

  char* ws = (char*)d_ws;
  _Float16* whT = (_Float16*)ws;             // 1,310,720 B
  float* mf = (float*)(ws + 1310720);        // 64*640*4 = 163,840 B
  int*   mi = (int*)  (ws + 1474560);        // 163,840 B

  // wsplit also zeroes mf+mi (327,680 B = 81,920 threads x 4 B)
  wsplit_kernel<<<(GV * C_DIM / 8) / 256, 256, 0, stream>>>(W, whT, (int*)mf);

  fused_kernel<<<FBLKS, 512, 0, stream>>>(x, whT, b, gn, cb, out, mf, mi);

  finalize_kernel<<<1, 640, 0, stream>>>(mf, mi, out + (size_t)N_ROWS * 512);
}

// Round 8
// 206.531 us; speedup vs baseline: 1.0179x; 1.0179x over previous
//
#include <hip/hip_runtime.h>

// Problem constants
#define N_ROWS 16384   // B*T
#define C_DIM  1024
#define GV     640     // G*V
#define V_DIM  320
#define G_DIM  2
#define D_DIM  256
#define MROWS  32      // rows per fused block (32 -> 49KB LDS -> 2 blocks/CU)
#define FBLKS  (N_ROWS / MROWS)  // 512 = 2 blocks/CU
#define NBUCKET 64

typedef __attribute__((ext_vector_type(8))) _Float16 half8;
typedef __attribute__((ext_vector_type(2))) _Float16 half2v;
typedef __attribute__((ext_vector_type(4))) float float4v;

#define LDS_AS(p) ((__attribute__((address_space(3))) unsigned int*)(p))
#define GLB_AS(p) ((const __attribute__((address_space(1))) unsigned int*)(p))

// ---------------- W -> fp16 hi, pre-swizzled into 16B-chunk-transposed layout ----
// whT[((kb*4 + c)*640 + n)*8 + h] = (half)W[n][kb*32 + c*8 + h]
// Also zeroes the mf/mi atomic-partial region (81,920 threads x 4 B = 327,680 B).
__global__ __launch_bounds__(256) void wsplit_kernel(const float* __restrict__ src,
                                                     _Float16* __restrict__ dst,
                                                     int* __restrict__ zr) {
  const int t = blockIdx.x * 256 + threadIdx.x;  // 0..81919
  zr[t] = 0;
  const int n = t % GV;
  const int cc = t / GV;       // 0..127 ; k = cc*8
  const int k = cc * 8;
  const float4 v0 = *(const float4*)(src + (size_t)n * C_DIM + k);
  const float4 v1 = *(const float4*)(src + (size_t)n * C_DIM + k + 4);
  half8 h;
  h[0] = (_Float16)v0.x; h[1] = (_Float16)v0.y; h[2] = (_Float16)v0.z; h[3] = (_Float16)v0.w;
  h[4] = (_Float16)v1.x; h[5] = (_Float16)v1.y; h[6] = (_Float16)v1.z; h[7] = (_Float16)v1.w;
  *(half8*)(dst + (size_t)t * 8) = h;
}

// ---------------- Fused: GEMM (M=32 x N=640 per block) + in-acc epilogue ----------
// Occupancy-first config: single-buffered B (40,960 B) + single-buffered A
// (8,192 B) = 49,152 B LDS -> 2 blocks/CU, 4 waves/SIMD. Rationale: rounds 1/7
// proved the GEMM phase is invariant to staging-pipeline structure (dbuf, counted
// vmcnt all null), while the epilogue (~55 us of the 93) is latency-serialized at
// 1.7 waves/SIMD. 2 blocks/CU doubles latency hiding for BOTH phases (cross-block
// overlap absorbs the per-iter barrier drains; epilogue chains overlap 2x) and
// halves per-wave epilogue work (8 row-tasks).
// GEMM loop = round-0's proven 2-barrier structure. Epilogue = round-6's in-acc
// design (identical reduction order -> bit-identical results), 32-row scaled.
__global__ __launch_bounds__(512, 4) void fused_kernel(
    const float* __restrict__ x,       // [N_ROWS, C_DIM] fp32
    const _Float16* __restrict__ whT,  // swizzled fp16 hi of W
    const float* __restrict__ bias,    // [GV]
    const float* __restrict__ gn,      // [2*N_ROWS, V_DIM]
    const float* __restrict__ cb,      // [GV, D_DIM]
    float* __restrict__ q,             // [N_ROWS, 512]
    float* __restrict__ mf,            // [NBUCKET, GV] atomic softmax partials (pre-zeroed)
    int* __restrict__ mi) {            // [NBUCKET, GV] atomic argmax counts (pre-zeroed)
  // LDS map: GEMM: B 40960 | A-hi 4096 | A-lo 4096 = 49152 B
  //   epilogue reuse: combW[64 rows][36 dwords] = 9,216 B ; wbL[64][4] at +9216
  __shared__ __align__(16) char smemU[49152];
  _Float16* BhL = (_Float16*)smemU;
  _Float16* AhL = (_Float16*)(smemU + 40960);
  _Float16* AlL = (_Float16*)(smemU + 45056);
  float* combW  = (float*)smemU;
  float* wbL    = (float*)(smemU + 9216);
  __shared__ float accL[GV];
  __shared__ int   cntL[GV];

  const int tid = threadIdx.x;
  const int lane = tid & 63;
  const int w = tid >> 6;          // wave 0..7
  const int m0 = blockIdx.x * MROWS;
  const int frow = lane & 15;
  const int quad = lane >> 4;

  for (int e = tid; e < GV; e += 512) { accL[e] = 0.0f; cntL[e] = 0; }

  // A staging map: thread -> (row ar, k-pair ak) of 32x32 fp32 tile
  const int ar = tid >> 4;           // 0..31
  const int ak = (tid & 15) * 2;     // 0..30 even
  const int ac = ak >> 3;            // chunk 0..3
  const int ah_off = ak & 7;         // within-chunk half offset (even)
  const float* xp = x + (size_t)(m0 + ar) * C_DIM + ak;

  float4v acc[2][5];
#pragma unroll
  for (int i = 0; i < 2; ++i)
#pragma unroll
    for (int j = 0; j < 5; ++j) acc[i][j] = (float4v)0.0f;

  float2 a2 = *(const float2*)xp;    // prefetch kb=0

  for (int kb = 0; kb < 32; ++kb) {
    // B staging: 2560 chunks x 16B, lane-linear both sides
    const _Float16* bsrc = whT + (size_t)kb * 2560 * 8;
#pragma unroll
    for (int s = 0; s < 5; ++s) {
      const int c = s * 512 + tid;
      __builtin_amdgcn_global_load_lds(GLB_AS(bsrc + (size_t)c * 8),
                                       LDS_AS(BhL + c * 8), 16, 0, 0);
    }
    // A: in-register split of prefetched fp32, store to [c][row] layout
    const _Float16 h0 = (_Float16)a2.x, h1 = (_Float16)a2.y;
    half2v hv, lv;
    hv.x = h0; hv.y = h1;
    lv.x = (_Float16)(a2.x - (float)h0);
    lv.y = (_Float16)(a2.y - (float)h1);
    *(half2v*)&AhL[(ac * 32 + ar) * 8 + ah_off] = hv;
    *(half2v*)&AlL[(ac * 32 + ar) * 8 + ah_off] = lv;
    if (kb < 31) a2 = *(const float2*)(xp + (kb + 1) * 32);  // rides the vmcnt drain
    __syncthreads();

    half8 ah[2], al[2];
#pragma unroll
    for (int i = 0; i < 2; ++i) {
      ah[i] = *(const half8*)&AhL[(quad * 32 + 16 * i + frow) * 8];
      al[i] = *(const half8*)&AlL[(quad * 32 + 16 * i + frow) * 8];
    }
#pragma unroll
    for (int j = 0; j < 5; ++j) {
      const half8 bh = *(const half8*)&BhL[(quad * 640 + 80 * w + 16 * j + frow) * 8];
#pragma unroll
      for (int i = 0; i < 2; ++i) {
        acc[i][j] = __builtin_amdgcn_mfma_f32_16x16x32_f16(ah[i], bh, acc[i][j], 0, 0, 0);
        acc[i][j] = __builtin_amdgcn_mfma_f32_16x16x32_f16(al[i], bh, acc[i][j], 0, 0, 0);
      }
    }
    __syncthreads();   // protect BhL/AhL overwrite next iter; last iter: LDS reuse safe
  }

  // bias for this wave's cols
  float bw[5];
#pragma unroll
  for (int j = 0; j < 5; ++j) bw[j] = bias[80 * w + 16 * j + frow];

  const int g  = w >> 2;   // group handled by this wave
  const int wq = w & 3;    // col-slice within group: cols 80*wq + 16j + frow

  // -------- Phase A: per-row wave-slice reductions (8 row-tasks, fully unrolled) --
  float mlk[2][4];   // per-row wave-slice l-max (basis of stored e')
#pragma unroll
  for (int i = 0; i < 2; ++i) {
#pragma unroll
    for (int r = 0; r < 4; ++r) {
      const int row = 16 * i + 4 * quad + r;
      const int n = m0 + row;
      const float* gp = gn + (size_t)(2 * n + g) * V_DIM + 80 * wq + frow;

      float l5[5], t5[5];
#pragma unroll
      for (int j = 0; j < 5; ++j) {
        l5[j] = acc[i][j][r] + bw[j];
        t5[j] = (l5[j] + gp[16 * j]) * 0.5f;
      }
      // in-lane max + argmax (ascending j: strict > keeps first index)
      float ml = l5[0]; int il = 80 * wq + frow;
      float mt = t5[0]; int it = il;
#pragma unroll
      for (int j = 1; j < 5; ++j) {
        const int cj = 80 * wq + 16 * j + frow;
        if (l5[j] > ml) { ml = l5[j]; il = cj; }
        if (t5[j] > mt) { mt = t5[j]; it = cj; }
      }
      // 16-lane butterfly (stays within quad-group for off<16)
#pragma unroll
      for (int off = 1; off < 16; off <<= 1) {
        const float o1 = __shfl_xor(ml, off, 64); const int i1 = __shfl_xor(il, off, 64);
        if (o1 > ml || (o1 == ml && i1 < il)) { ml = o1; il = i1; }
        const float o2 = __shfl_xor(mt, off, 64); const int i2 = __shfl_xor(it, off, 64);
        if (o2 > mt || (o2 == mt && i2 < it)) { mt = o2; it = i2; }
      }
      mlk[i][r] = ml;
      // online partial sums vs wave-slice max; keep e' in acc regs
      float sl = 0.0f, st = 0.0f;
#pragma unroll
      for (int j = 0; j < 5; ++j) {
        const float el = expf(l5[j] - ml);
        acc[i][j][r] = el;
        sl += el;
        st += expf(t5[j] - mt);
      }
#pragma unroll
      for (int off = 1; off < 16; off <<= 1) {
        sl += __shfl_xor(sl, off, 64);
        st += __shfl_xor(st, off, 64);
      }
      // one writer lane per (i,r): 2 x b128 partials
      if (frow == 4 * i + r) {
        float* dst = combW + (size_t)(g * 32 + row) * 36 + wq * 8;
        float4v p1, p2;
        p1[0] = ml; p1[1] = __int_as_float(il); p1[2] = sl; p1[3] = 0.0f;
        p2[0] = mt; p2[1] = __int_as_float(it); p2[2] = st; p2[3] = 0.0f;
        *(float4v*)dst = p1;
        *(float4v*)(dst + 4) = p2;
      }
    }
  }
  __syncthreads();

  // -------- Phase A2: combine 4 wave partials per row (64 rows, 64 threads) ----
  if (tid < 64) {
    const int rg = tid;                // g*32 + row
    const float* cw = combW + (size_t)rg * 36;
    float mw[4], sw[4], tw[4], s2[4];
    int   iw[4], ti4[4];
#pragma unroll
    for (int v = 0; v < 4; ++v) {
      const float4v p1 = *(const float4v*)(cw + v * 8);
      const float4v p2 = *(const float4v*)(cw + v * 8 + 4);
      mw[v] = p1[0]; iw[v] = __float_as_int(p1[1]); sw[v] = p1[2];
      tw[v] = p2[0]; ti4[v] = __float_as_int(p2[1]); s2[v] = p2[2];
    }
    float m = mw[0]; int idx = iw[0];
    float tm = tw[0]; int ti = ti4[0];
#pragma unroll
    for (int v = 1; v < 4; ++v) {
      if (mw[v] > m || (mw[v] == m && iw[v] < idx)) { m = mw[v]; idx = iw[v]; }
      if (tw[v] > tm || (tw[v] == tm && ti4[v] < ti)) { tm = tw[v]; ti = ti4[v]; }
    }
    float sl = 0.0f, st = 0.0f;
#pragma unroll
    for (int v = 0; v < 4; ++v) {
      sl += sw[v] * expf(mw[v] - m);
      st += s2[v] * expf(tw[v] - tm);
    }
    const float inv = 1.0f / sl;
    const float sv = 1.0f / st;
    const float yv = (1.0f + sv) - sv;   // straight-through value at argmax
    const int g2 = rg >> 5;
    atomicAdd(&cntL[g2 * V_DIM + idx], 1);
    float4v wbv;
    wbv[0] = m; wbv[1] = inv; wbv[2] = yv; wbv[3] = __int_as_float(ti);
    *(float4v*)(wbL + (size_t)rg * 4) = wbv;
  }
  __syncthreads();

  // -------- Phase CD: accL accumulation + q writes --------
  float p5[5] = {0.0f, 0.0f, 0.0f, 0.0f, 0.0f};
#pragma unroll
  for (int i = 0; i < 2; ++i)
#pragma unroll
    for (int r = 0; r < 4; ++r) {
      const int row = 16 * i + 4 * quad + r;
      const float4v wbv = *(const float4v*)(wbL + (size_t)(g * 32 + row) * 4);
      const float k = expf(mlk[i][r] - wbv[0]) * wbv[1];
#pragma unroll
      for (int j = 0; j < 5; ++j) p5[j] += acc[i][j][r] * k;
    }
#pragma unroll
  for (int j = 0; j < 5; ++j)
    atomicAdd(&accL[g * V_DIM + 80 * wq + 16 * j + frow], p5[j]);  // 4-way contention

  // q: 64 tasks x 64 float4; one wave per task per iteration, fully coalesced
#pragma unroll
  for (int it2 = 0; it2 < 8; ++it2) {
    const int task = w + 8 * it2;          // 0..63 = g*32 + row
    const int tg = task >> 5, trow = task & 31;
    const float4v wbv = *(const float4v*)(wbL + (size_t)task * 4);  // broadcast
    const float yv = wbv[2];
    const int ti = __float_as_int(wbv[3]);
    const float4v c4 = ((const float4v*)cb)[(size_t)(tg * V_DIM + ti) * 64 + lane];
    float4v o4;
#pragma unroll
    for (int e2 = 0; e2 < 4; ++e2) o4[e2] = yv * c4[e2];
    ((float4v*)q)[(size_t)(m0 + trow) * 128 + tg * 64 + lane] = o4;
  }

  __syncthreads();
  const size_t pb = (size_t)(blockIdx.x & (NBUCKET - 1)) * GV;
  for (int e = tid; e < GV; e += 512) {
    atomicAdd(&mf[pb + e], accL[e]);
    atomicAdd(&mi[pb + e], cntL[e]);
  }
}

// ---------------- Finalize: sum 64 buckets, entropies, outputs ----------------
__global__ __launch_bounds__(640) void finalize_kernel(
    const float* __restrict__ mf, const int* __restrict__ mi,
    float* __restrict__ out3) {
  __shared__ float sA[G_DIM];
  __shared__ float sC[G_DIM];
  const int t = threadIdx.x;        // 0..639 == e
  if (t < G_DIM) { sA[t] = 0.0f; sC[t] = 0.0f; }
  __syncthreads();

  const int g = t / V_DIM;          // wave-uniform
  float f = 0.0f;
  int   c = 0;
#pragma unroll 8
  for (int b = 0; b < NBUCKET; ++b) {
    f += mf[(size_t)b * GV + t];
    c += mi[(size_t)b * GV + t];
  }
  const float pa = f * (1.0f / 16384.0f);
  const float ph = (float)c * (1.0f / 16384.0f);
  float a = pa * logf(pa + 1e-7f);
  float h = ph * logf(ph + 1e-7f);
#pragma unroll
  for (int off = 32; off > 0; off >>= 1) {
    a += __shfl_xor(a, off, 64);
    h += __shfl_xor(h, off, 64);
  }
  if ((t & 63) == 0) {
    atomicAdd(&sA[g], a);
    atomicAdd(&sC[g], h);
  }
  __syncthreads();
  if (t == 0) {
    const float code_p = expf(-sC[0]) + expf(-sC[1]);
    const float prob_p = expf(-sA[0]) + expf(-sA[1]);
    out3[0] = code_p;
    out3[1] = prob_p;
    out3[2] = ((float)GV - prob_p) / (float)GV;
  }
}

extern "C" void kernel_launch(void* const* d_in, const int* in_sizes, int n_in,
                              void* d_out, int out_size, void* d_ws, size_t ws_size,
                              hipStream_t stream) {
  const float* x  = (const float*)d_in[0];  // [8,2048,1024]
  const float* W  = (const float*)d_in[1];  // [640,1024]
  const float* b  = (const float*)d_in[2];  // [640]
  const float* cb = (const float*)d_in[3];  // [1,640,256]
  const float* gn = (const float*)d_in[4];  // [32768,320]
  float* out = (float*)d_out;               // q [16384*512] + 3 scalars

  char* ws = (char*)d_ws;
  _Float16* whT = (_Float16*)ws;             // 1,310,720 B
  float* mf = (float*)(ws + 1310720);        // 64*640*4 = 163,840 B
  int*   mi = (int*)  (ws + 1474560);        // 163,840 B

  // wsplit also zeroes mf+mi (327,680 B = 81,920 threads x 4 B)
  wsplit_kernel<<<(GV * C_DIM / 8) / 256, 256, 0, stream>>>(W, whT, (int*)mf);

  fused_kernel<<<FBLKS, 512, 0, stream>>>(x, whT, b, gn, cb, out, mf, mi);

  finalize_kernel<<<1, 640, 0, stream>>>(mf, mi, out + (size_t)N_ROWS * 512);
}